// Round 1
// baseline (468.435 us; speedup 1.0000x reference)
//
#include <hip/hip_runtime.h>
#include <cstddef>

// Problem constants (fixed by the benchmark)
namespace {
constexpr int cB = 32;      // batch
constexpr int cG = 2704;    // grid cells (52*52)
constexpr int cA = 3;       // anchors
constexpr int cC = 6;       // channels per box
constexpr int cD = 1024;    // feature depth
constexpr int cL = 20;      // text tokens
constexpr int cH = 512;     // hidden
constexpr int cK = 128;     // select_num (scalar input, fixed = 128)
constexpr int ROWS_OUT = cK + cL;  // 148
}

// ---------------------------------------------------------------------------
// Kernel 1: per-batch top-K via 8-bit radix select on sortable uints.
// One 256-thread block per batch. Emits selected grid indices in ASCENDING
// order (matches jnp.sort(top_k_idx)); ties at the threshold take lowest
// indices first (matches lax.top_k tie-breaking).
// ---------------------------------------------------------------------------
__global__ __launch_bounds__(256) void topk_kernel(
    const float* __restrict__ boxes, int* __restrict__ idx_out) {
  const int b = blockIdx.x;
  const int tid = threadIdx.x;
  __shared__ unsigned su[cG];
  __shared__ int hist[256];
  __shared__ int s_rem;
  __shared__ unsigned s_prefix;

  // score = mean over anchors of channel 4
  for (int g = tid; g < cG; g += 256) {
    const float* p = boxes + ((size_t)(b * cG + g) * cA) * cC + 4;
    float s = (p[0] + p[cC] + p[2 * cC]) * (1.0f / 3.0f);
    unsigned bits = __float_as_uint(s);
    su[g] = (bits & 0x80000000u) ? ~bits : (bits | 0x80000000u);
  }
  __syncthreads();

  int remaining = cK;
  unsigned prefix = 0;
  for (int pass = 0; pass < 4; ++pass) {
    const int shift = 24 - 8 * pass;
    for (int i = tid; i < 256; i += 256) hist[i] = 0;
    __syncthreads();
    for (int g = tid; g < cG; g += 256) {
      unsigned u = su[g];
      bool match = (pass == 0) || ((u >> (shift + 8)) == (prefix >> (shift + 8)));
      if (match) atomicAdd(&hist[(u >> shift) & 255], 1);
    }
    __syncthreads();
    if (tid == 0) {
      int acc = 0;
      int v = 255;
      for (; v > 0; --v) {
        if (acc + hist[v] >= remaining) break;
        acc += hist[v];
      }
      s_rem = remaining - acc;
      s_prefix = prefix | ((unsigned)v << shift);
    }
    __syncthreads();
    remaining = s_rem;
    prefix = s_prefix;
    __syncthreads();
  }

  // prefix == threshold value; `remaining` elements equal to it are included
  // (lowest indices first). Serial emission in ascending g: 2704 iters, cheap.
  if (tid == 0) {
    int pos = 0, need = remaining;
    for (int g = 0; g < cG && pos < cK; ++g) {
      unsigned u = su[g];
      if (u > prefix) {
        idx_out[b * cK + pos++] = g;
      } else if (u == prefix && need > 0) {
        idx_out[b * cK + pos++] = g;
        --need;
      }
    }
  }
}

// ---------------------------------------------------------------------------
// Kernel 2: gather selected boxes -> out2 [B, K, A, C]
// ---------------------------------------------------------------------------
__global__ __launch_bounds__(256) void gather_boxes_kernel(
    const float* __restrict__ boxes, const int* __restrict__ idx,
    float* __restrict__ out2) {
  int t = blockIdx.x * 256 + threadIdx.x;
  constexpr int N = cB * cK * cA * cC;
  if (t >= N) return;
  int e = t % (cA * cC);
  int bk = t / (cA * cC);
  int b = bk / cK;
  int g = idx[bk];
  out2[t] = boxes[((size_t)(b * cG + g)) * (cA * cC) + e];
}

// ---------------------------------------------------------------------------
// Kernel 3: gather sel_feat [B*K, D] (row-major) from feature [B, D, G].
// Reads: 64 lanes hit 64 scattered g's within ONE feature row (line reuse);
// writes: transposed through padded LDS tile -> fully coalesced.
// grid: (K/64, D/64, B), 256 threads.
// ---------------------------------------------------------------------------
__global__ __launch_bounds__(256) void gather_feat_kernel(
    const float* __restrict__ feature, const int* __restrict__ idx,
    float* __restrict__ selfeat) {
  const int kc = blockIdx.x, dc = blockIdx.y, b = blockIdx.z;
  const int lane = threadIdx.x & 63;
  const int grp = threadIdx.x >> 6;  // 0..3
  __shared__ int sidx[64];
  __shared__ float tile[64][65];  // [d][k], pad +1 breaks transpose conflicts
  if (threadIdx.x < 64) sidx[threadIdx.x] = idx[b * cK + kc * 64 + threadIdx.x];
  __syncthreads();

  const size_t fbase = (size_t)b * cD * cG + (size_t)(dc * 64) * cG;
  const int g = sidx[lane];
  for (int dd = grp; dd < 64; dd += 4) {
    tile[dd][lane] = feature[fbase + (size_t)dd * cG + g];
  }
  __syncthreads();

  const size_t obase = ((size_t)(b * cK + kc * 64)) * cD + dc * 64;
  for (int kk = grp; kk < 64; kk += 4) {
    selfeat[obase + (size_t)kk * cD + lane] = tile[lane][kk];
  }
}

// ---------------------------------------------------------------------------
// Kernel 4: f32 tiled GEMM with fused bias + packed-output row remap.
// C[row, col] = sum_d Ap[row, d] * Bw[d, col] + bias[col]
// out layout: out[bb * (148*512) + (row_off + row%rpb)*512 + col]
// BM=BN=64, BK=16, 256 threads, 4x4 accumulators per thread.
// ---------------------------------------------------------------------------
__global__ __launch_bounds__(256) void gemm_kernel(
    const float* __restrict__ Ap, const float* __restrict__ Bw,
    const float* __restrict__ bias, float* __restrict__ out, int Kd, int rpb,
    int row_off) {
  const int bm = blockIdx.x, bn = blockIdx.y;
  const int tid = threadIdx.x;
  __shared__ float As[16][68];  // pad to 68 -> 16B-aligned float4 rows
  __shared__ float Bs[16][64];

  const int tr = tid >> 4, tc = tid & 15;
  float acc[4][4] = {};

  // A-load mapping: m = tid>>2 (64 rows), dk4 = tid&3 (4 groups of 4)
  const int a_m = tid >> 2;
  const int a_dk = (tid & 3) * 4;
  // B-load mapping: dk = tid>>4 (16), n4 = tid&15
  const int b_dk = tid >> 4;
  const int b_n = (tid & 15) * 4;

  const int nsteps = Kd >> 4;
  for (int kt = 0; kt < nsteps; ++kt) {
    const float4 av = *(const float4*)(Ap + (size_t)(bm * 64 + a_m) * Kd +
                                       kt * 16 + a_dk);
    As[a_dk + 0][a_m] = av.x;
    As[a_dk + 1][a_m] = av.y;
    As[a_dk + 2][a_m] = av.z;
    As[a_dk + 3][a_m] = av.w;
    const float4 bv = *(const float4*)(Bw + (size_t)(kt * 16 + b_dk) * cH +
                                       bn * 64 + b_n);
    *(float4*)&Bs[b_dk][b_n] = bv;
    __syncthreads();

#pragma unroll
    for (int dk = 0; dk < 16; ++dk) {
      const float4 a4 = *(const float4*)&As[dk][tr * 4];
      const float4 b4 = *(const float4*)&Bs[dk][tc * 4];
      acc[0][0] += a4.x * b4.x; acc[0][1] += a4.x * b4.y;
      acc[0][2] += a4.x * b4.z; acc[0][3] += a4.x * b4.w;
      acc[1][0] += a4.y * b4.x; acc[1][1] += a4.y * b4.y;
      acc[1][2] += a4.y * b4.z; acc[1][3] += a4.y * b4.w;
      acc[2][0] += a4.z * b4.x; acc[2][1] += a4.z * b4.y;
      acc[2][2] += a4.z * b4.z; acc[2][3] += a4.z * b4.w;
      acc[3][0] += a4.w * b4.x; acc[3][1] += a4.w * b4.y;
      acc[3][2] += a4.w * b4.z; acc[3][3] += a4.w * b4.w;
    }
    __syncthreads();
  }

  const int col = bn * 64 + tc * 4;
  const float4 bias4 = *(const float4*)(bias + col);
#pragma unroll
  for (int i = 0; i < 4; ++i) {
    const int row = bm * 64 + tr * 4 + i;
    const int bb = row / rpb;
    const int rr = row - bb * rpb;
    float4 v;
    v.x = acc[i][0] + bias4.x;
    v.y = acc[i][1] + bias4.y;
    v.z = acc[i][2] + bias4.z;
    v.w = acc[i][3] + bias4.w;
    *(float4*)(out + (size_t)bb * (ROWS_OUT * cH) +
               (size_t)(row_off + rr) * cH + col) = v;
  }
}

// ---------------------------------------------------------------------------
extern "C" void kernel_launch(void* const* d_in, const int* in_sizes, int n_in,
                              void* d_out, int out_size, void* d_ws,
                              size_t ws_size, hipStream_t stream) {
  const float* boxes = (const float*)d_in[0];
  const float* feature = (const float*)d_in[1];
  const float* text = (const float*)d_in[2];
  const float* W_vs = (const float*)d_in[3];
  const float* b_vs = (const float*)d_in[4];
  const float* W_tx = (const float*)d_in[5];
  const float* b_tx = (const float*)d_in[6];
  // d_in[7] = select_num (always 128; grid dims depend on it -> hard-coded)

  float* out = (float*)d_out;                       // [B, 148, 512]
  float* out_boxes = out + (size_t)cB * ROWS_OUT * cH;  // [B, K, 3, 6]

  // workspace layout: idx [B*K int] at 0; sel_feat [B*K, D] f32 at +16KB
  int* idx = (int*)d_ws;
  float* selfeat = (float*)((char*)d_ws + 16384);

  // 1) top-K indices per batch (ascending)
  topk_kernel<<<cB, 256, 0, stream>>>(boxes, idx);

  // 2) gather selected boxes
  {
    constexpr int N = cB * cK * cA * cC;
    gather_boxes_kernel<<<(N + 255) / 256, 256, 0, stream>>>(boxes, idx,
                                                             out_boxes);
  }

  // 3) gather selected feature columns -> sel_feat [B*K, D]
  {
    dim3 grid(cK / 64, cD / 64, cB);
    gather_feat_kernel<<<grid, 256, 0, stream>>>(feature, idx, selfeat);
  }

  // 4) linear_feature = sel_feat @ W_vs + b_vs -> out rows [0,128)
  {
    dim3 grid((cB * cK) / 64, cH / 64);
    gemm_kernel<<<grid, 256, 0, stream>>>(selfeat, W_vs, b_vs, out, cD, cK, 0);
  }

  // 5) linear_text = text @ W_tx + b_tx -> out rows [128,148)
  {
    dim3 grid((cB * cL) / 64, cH / 64);
    gemm_kernel<<<grid, 256, 0, stream>>>(text, W_tx, b_tx, out, cH, cL, cK);
  }
}

// Round 2
// 197.570 us; speedup vs baseline: 2.3710x; 2.3710x over previous
//
#include <hip/hip_runtime.h>
#include <cstddef>

// Problem constants (fixed by the benchmark)
namespace {
constexpr int cB = 32;      // batch
constexpr int cG = 2704;    // grid cells (52*52)
constexpr int cA = 3;       // anchors
constexpr int cC = 6;       // channels per box
constexpr int cD = 1024;    // feature depth
constexpr int cL = 20;      // text tokens
constexpr int cH = 512;     // hidden
constexpr int cK = 128;     // select_num (scalar input, fixed = 128)
constexpr int ROWS_OUT = cK + cL;  // 148
constexpr int CHUNK = (cG + 255) / 256;  // 11 cells per thread
}

// ---------------------------------------------------------------------------
// Kernel 1: per-batch top-K via 8-bit radix select on sortable uints.
// One 256-thread block per batch. FULLY PARALLEL: threshold found via
// parallel suffix-scan of the histogram; emission via block-wide stream
// compaction (prefix scan over per-thread chunk counts). Emits selected grid
// indices in ASCENDING order (matches jnp.sort(top_k_idx)); ties at the
// threshold take lowest indices first (matches lax.top_k tie-breaking).
// ---------------------------------------------------------------------------
__global__ __launch_bounds__(256) void topk_kernel(
    const float* __restrict__ boxes, int* __restrict__ idx_out) {
  const int b = blockIdx.x;
  const int tid = threadIdx.x;
  __shared__ unsigned su[cG];
  __shared__ int hist[256];
  __shared__ int scan[256];
  __shared__ int s_rem;
  __shared__ unsigned s_prefix;

  // score = mean over anchors of channel 4, mapped to sortable uint
  for (int g = tid; g < cG; g += 256) {
    const float* p = boxes + ((size_t)(b * cG + g) * cA) * cC + 4;
    float s = (p[0] + p[cC] + p[2 * cC]) * (1.0f / 3.0f);
    unsigned bits = __float_as_uint(s);
    su[g] = (bits & 0x80000000u) ? ~bits : (bits | 0x80000000u);
  }
  __syncthreads();

  int remaining = cK;
  unsigned prefix = 0;
  for (int pass = 0; pass < 4; ++pass) {
    const int shift = 24 - 8 * pass;
    hist[tid] = 0;
    __syncthreads();
    for (int g = tid; g < cG; g += 256) {
      unsigned u = su[g];
      bool match =
          (pass == 0) || ((u >> (shift + 8)) == (prefix >> (shift + 8)));
      if (match) atomicAdd(&hist[(u >> shift) & 255], 1);
    }
    __syncthreads();

    // parallel inclusive SUFFIX scan: scan[v] = sum_{j>=v} hist[j]
    scan[tid] = hist[tid];
    __syncthreads();
    for (int off = 1; off < 256; off <<= 1) {
      int v = scan[tid];
      int w = (tid + off < 256) ? scan[tid + off] : 0;
      __syncthreads();
      scan[tid] = v + w;
      __syncthreads();
    }
    // crossing bucket: largest v with suffix(v) >= remaining
    {
      int sv = scan[tid];
      int sv_next = (tid == 255) ? 0 : scan[tid + 1];
      if (sv >= remaining && sv_next < remaining) {
        s_prefix = prefix | ((unsigned)tid << shift);
        s_rem = remaining - sv_next;
      }
    }
    __syncthreads();
    remaining = s_rem;
    prefix = s_prefix;
    __syncthreads();
  }

  // ---- stream compaction: emit selected g's in ascending order ----
  // thread t owns contiguous cells [t*CHUNK, min((t+1)*CHUNK, cG))
  const int g0 = tid * CHUNK;
  const int g1 = min(g0 + CHUNK, cG);
  int cgt = 0, ceq = 0;
  for (int g = g0; g < g1; ++g) {
    unsigned u = su[g];
    cgt += (u > prefix);
    ceq += (u == prefix);
  }
  // pack (gt,eq) into one int: 16 bits each (totals <= 2704)
  int packed = (cgt << 16) | ceq;
  scan[tid] = packed;
  __syncthreads();
  for (int off = 1; off < 256; off <<= 1) {
    int v = scan[tid];
    int w = (tid >= off) ? scan[tid - off] : 0;
    __syncthreads();
    scan[tid] = v + w;
    __syncthreads();
  }
  int excl = scan[tid] - packed;  // exclusive prefix
  int gt_before = excl >> 16;
  int eq_before = excl & 0xffff;

  for (int g = g0; g < g1; ++g) {
    unsigned u = su[g];
    if (u > prefix) {
      int pos = gt_before + min(eq_before, remaining);
      idx_out[b * cK + pos] = g;
      ++gt_before;
    } else if (u == prefix) {
      if (eq_before < remaining) {
        int pos = gt_before + eq_before;
        idx_out[b * cK + pos] = g;
      }
      ++eq_before;
    }
  }
}

// ---------------------------------------------------------------------------
// Kernel 2: gather selected boxes -> out2 [B, K, A, C]
// ---------------------------------------------------------------------------
__global__ __launch_bounds__(256) void gather_boxes_kernel(
    const float* __restrict__ boxes, const int* __restrict__ idx,
    float* __restrict__ out2) {
  int t = blockIdx.x * 256 + threadIdx.x;
  constexpr int N = cB * cK * cA * cC;
  if (t >= N) return;
  int e = t % (cA * cC);
  int bk = t / (cA * cC);
  int b = bk / cK;
  int g = idx[bk];
  out2[t] = boxes[((size_t)(b * cG + g)) * (cA * cC) + e];
}

// ---------------------------------------------------------------------------
// Kernel 3: gather sel_feat [B*K, D] (row-major) from feature [B, D, G].
// Reads: 64 lanes hit 64 scattered g's within ONE feature row (line reuse);
// writes: transposed through padded LDS tile -> fully coalesced.
// grid: (K/64, D/64, B), 256 threads.
// ---------------------------------------------------------------------------
__global__ __launch_bounds__(256) void gather_feat_kernel(
    const float* __restrict__ feature, const int* __restrict__ idx,
    float* __restrict__ selfeat) {
  const int kc = blockIdx.x, dc = blockIdx.y, b = blockIdx.z;
  const int lane = threadIdx.x & 63;
  const int grp = threadIdx.x >> 6;  // 0..3
  __shared__ int sidx[64];
  __shared__ float tile[64][65];  // [d][k], pad +1 breaks transpose conflicts
  if (threadIdx.x < 64) sidx[threadIdx.x] = idx[b * cK + kc * 64 + threadIdx.x];
  __syncthreads();

  const size_t fbase = (size_t)b * cD * cG + (size_t)(dc * 64) * cG;
  const int g = sidx[lane];
  for (int dd = grp; dd < 64; dd += 4) {
    tile[dd][lane] = feature[fbase + (size_t)dd * cG + g];
  }
  __syncthreads();

  const size_t obase = ((size_t)(b * cK + kc * 64)) * cD + dc * 64;
  for (int kk = grp; kk < 64; kk += 4) {
    selfeat[obase + (size_t)kk * cD + lane] = tile[lane][kk];
  }
}

// ---------------------------------------------------------------------------
// Kernel 4: f32 tiled GEMM with fused bias + packed-output row remap.
// C[row, col] = sum_d Ap[row, d] * Bw[d, col] + bias[col]
// out layout: out[bb * (148*512) + (row_off + row%rpb)*512 + col]
// BM=BN=64, BK=16, 256 threads, 4x4 accumulators per thread.
// ---------------------------------------------------------------------------
__global__ __launch_bounds__(256) void gemm_kernel(
    const float* __restrict__ Ap, const float* __restrict__ Bw,
    const float* __restrict__ bias, float* __restrict__ out, int Kd, int rpb,
    int row_off) {
  const int bm = blockIdx.x, bn = blockIdx.y;
  const int tid = threadIdx.x;
  __shared__ float As[16][68];  // pad to 68 -> 16B-aligned float4 rows
  __shared__ float Bs[16][64];

  const int tr = tid >> 4, tc = tid & 15;
  float acc[4][4] = {};

  // A-load mapping: m = tid>>2 (64 rows), dk4 = tid&3 (4 groups of 4)
  const int a_m = tid >> 2;
  const int a_dk = (tid & 3) * 4;
  // B-load mapping: dk = tid>>4 (16), n4 = tid&15
  const int b_dk = tid >> 4;
  const int b_n = (tid & 15) * 4;

  const int nsteps = Kd >> 4;
  for (int kt = 0; kt < nsteps; ++kt) {
    const float4 av = *(const float4*)(Ap + (size_t)(bm * 64 + a_m) * Kd +
                                       kt * 16 + a_dk);
    As[a_dk + 0][a_m] = av.x;
    As[a_dk + 1][a_m] = av.y;
    As[a_dk + 2][a_m] = av.z;
    As[a_dk + 3][a_m] = av.w;
    const float4 bv = *(const float4*)(Bw + (size_t)(kt * 16 + b_dk) * cH +
                                       bn * 64 + b_n);
    *(float4*)&Bs[b_dk][b_n] = bv;
    __syncthreads();

#pragma unroll
    for (int dk = 0; dk < 16; ++dk) {
      const float4 a4 = *(const float4*)&As[dk][tr * 4];
      const float4 b4 = *(const float4*)&Bs[dk][tc * 4];
      acc[0][0] += a4.x * b4.x; acc[0][1] += a4.x * b4.y;
      acc[0][2] += a4.x * b4.z; acc[0][3] += a4.x * b4.w;
      acc[1][0] += a4.y * b4.x; acc[1][1] += a4.y * b4.y;
      acc[1][2] += a4.y * b4.z; acc[1][3] += a4.y * b4.w;
      acc[2][0] += a4.z * b4.x; acc[2][1] += a4.z * b4.y;
      acc[2][2] += a4.z * b4.z; acc[2][3] += a4.z * b4.w;
      acc[3][0] += a4.w * b4.x; acc[3][1] += a4.w * b4.y;
      acc[3][2] += a4.w * b4.z; acc[3][3] += a4.w * b4.w;
    }
    __syncthreads();
  }

  const int col = bn * 64 + tc * 4;
  const float4 bias4 = *(const float4*)(bias + col);
#pragma unroll
  for (int i = 0; i < 4; ++i) {
    const int row = bm * 64 + tr * 4 + i;
    const int bb = row / rpb;
    const int rr = row - bb * rpb;
    float4 v;
    v.x = acc[i][0] + bias4.x;
    v.y = acc[i][1] + bias4.y;
    v.z = acc[i][2] + bias4.z;
    v.w = acc[i][3] + bias4.w;
    *(float4*)(out + (size_t)bb * (ROWS_OUT * cH) +
               (size_t)(row_off + rr) * cH + col) = v;
  }
}

// ---------------------------------------------------------------------------
extern "C" void kernel_launch(void* const* d_in, const int* in_sizes, int n_in,
                              void* d_out, int out_size, void* d_ws,
                              size_t ws_size, hipStream_t stream) {
  const float* boxes = (const float*)d_in[0];
  const float* feature = (const float*)d_in[1];
  const float* text = (const float*)d_in[2];
  const float* W_vs = (const float*)d_in[3];
  const float* b_vs = (const float*)d_in[4];
  const float* W_tx = (const float*)d_in[5];
  const float* b_tx = (const float*)d_in[6];
  // d_in[7] = select_num (always 128; grid dims depend on it -> hard-coded)

  float* out = (float*)d_out;                       // [B, 148, 512]
  float* out_boxes = out + (size_t)cB * ROWS_OUT * cH;  // [B, K, 3, 6]

  // workspace layout: idx [B*K int] at 0; sel_feat [B*K, D] f32 at +16KB
  int* idx = (int*)d_ws;
  float* selfeat = (float*)((char*)d_ws + 16384);

  // 1) top-K indices per batch (ascending)
  topk_kernel<<<cB, 256, 0, stream>>>(boxes, idx);

  // 2) gather selected boxes
  {
    constexpr int N = cB * cK * cA * cC;
    gather_boxes_kernel<<<(N + 255) / 256, 256, 0, stream>>>(boxes, idx,
                                                             out_boxes);
  }

  // 3) gather selected feature columns -> sel_feat [B*K, D]
  {
    dim3 grid(cK / 64, cD / 64, cB);
    gather_feat_kernel<<<grid, 256, 0, stream>>>(feature, idx, selfeat);
  }

  // 4) linear_feature = sel_feat @ W_vs + b_vs -> out rows [0,128)
  {
    dim3 grid((cB * cK) / 64, cH / 64);
    gemm_kernel<<<grid, 256, 0, stream>>>(selfeat, W_vs, b_vs, out, cD, cK, 0);
  }

  // 5) linear_text = text @ W_tx + b_tx -> out rows [128,148)
  {
    dim3 grid((cB * cL) / 64, cH / 64);
    gemm_kernel<<<grid, 256, 0, stream>>>(text, W_tx, b_tx, out, cH, cL, cK);
  }
}

// Round 3
// 133.547 us; speedup vs baseline: 3.5076x; 1.4794x over previous
//
#include <hip/hip_runtime.h>
#include <cstddef>

// Problem constants (fixed by the benchmark)
namespace {
constexpr int cB = 32;      // batch
constexpr int cG = 2704;    // grid cells (52*52)
constexpr int cA = 3;       // anchors
constexpr int cC = 6;       // channels per box
constexpr int cD = 1024;    // feature depth
constexpr int cL = 20;      // text tokens
constexpr int cH = 512;     // hidden
constexpr int cK = 128;     // select_num (scalar input, fixed = 128)
constexpr int ROWS_OUT = cK + cL;  // 148
constexpr int CHUNK = (cG + 255) / 256;  // 11 cells per thread
}

using u16x8 = __attribute__((ext_vector_type(8))) unsigned short;
using f32x4 = __attribute__((ext_vector_type(4))) float;
using bf16x8 = __attribute__((ext_vector_type(8))) short;

static __device__ __forceinline__ unsigned short f2bf(float f) {
  unsigned u = __float_as_uint(f);
  unsigned rounding = 0x7fffu + ((u >> 16) & 1u);
  return (unsigned short)((u + rounding) >> 16);
}
static __device__ __forceinline__ unsigned packbf(float lo, float hi) {
  return (unsigned)f2bf(lo) | ((unsigned)f2bf(hi) << 16);
}

// ---------------------------------------------------------------------------
// Kernel 1: per-batch top-K via 8-bit radix select on sortable uints.
// Fully parallel (suffix-scan threshold + stream-compaction emission).
// Emits ascending grid indices; ties take lowest indices first.
// ---------------------------------------------------------------------------
__global__ __launch_bounds__(256) void topk_kernel(
    const float* __restrict__ boxes, int* __restrict__ idx_out) {
  const int b = blockIdx.x;
  const int tid = threadIdx.x;
  __shared__ unsigned su[cG];
  __shared__ int hist[256];
  __shared__ int scan[256];
  __shared__ int s_rem;
  __shared__ unsigned s_prefix;

  for (int g = tid; g < cG; g += 256) {
    const float* p = boxes + ((size_t)(b * cG + g) * cA) * cC + 4;
    float s = (p[0] + p[cC] + p[2 * cC]) * (1.0f / 3.0f);
    unsigned bits = __float_as_uint(s);
    su[g] = (bits & 0x80000000u) ? ~bits : (bits | 0x80000000u);
  }
  __syncthreads();

  int remaining = cK;
  unsigned prefix = 0;
  for (int pass = 0; pass < 4; ++pass) {
    const int shift = 24 - 8 * pass;
    hist[tid] = 0;
    __syncthreads();
    for (int g = tid; g < cG; g += 256) {
      unsigned u = su[g];
      bool match =
          (pass == 0) || ((u >> (shift + 8)) == (prefix >> (shift + 8)));
      if (match) atomicAdd(&hist[(u >> shift) & 255], 1);
    }
    __syncthreads();

    scan[tid] = hist[tid];
    __syncthreads();
    for (int off = 1; off < 256; off <<= 1) {
      int v = scan[tid];
      int w = (tid + off < 256) ? scan[tid + off] : 0;
      __syncthreads();
      scan[tid] = v + w;
      __syncthreads();
    }
    {
      int sv = scan[tid];
      int sv_next = (tid == 255) ? 0 : scan[tid + 1];
      if (sv >= remaining && sv_next < remaining) {
        s_prefix = prefix | ((unsigned)tid << shift);
        s_rem = remaining - sv_next;
      }
    }
    __syncthreads();
    remaining = s_rem;
    prefix = s_prefix;
    __syncthreads();
  }

  const int g0 = tid * CHUNK;
  const int g1 = min(g0 + CHUNK, cG);
  int cgt = 0, ceq = 0;
  for (int g = g0; g < g1; ++g) {
    unsigned u = su[g];
    cgt += (u > prefix);
    ceq += (u == prefix);
  }
  int packed = (cgt << 16) | ceq;
  scan[tid] = packed;
  __syncthreads();
  for (int off = 1; off < 256; off <<= 1) {
    int v = scan[tid];
    int w = (tid >= off) ? scan[tid - off] : 0;
    __syncthreads();
    scan[tid] = v + w;
    __syncthreads();
  }
  int excl = scan[tid] - packed;
  int gt_before = excl >> 16;
  int eq_before = excl & 0xffff;

  for (int g = g0; g < g1; ++g) {
    unsigned u = su[g];
    if (u > prefix) {
      int pos = gt_before + min(eq_before, remaining);
      idx_out[b * cK + pos] = g;
      ++gt_before;
    } else if (u == prefix) {
      if (eq_before < remaining) {
        int pos = gt_before + eq_before;
        idx_out[b * cK + pos] = g;
      }
      ++eq_before;
    }
  }
}

// ---------------------------------------------------------------------------
// Kernel 2: gather selected boxes -> out2 [B, K, A, C]
// ---------------------------------------------------------------------------
__global__ __launch_bounds__(256) void gather_boxes_kernel(
    const float* __restrict__ boxes, const int* __restrict__ idx,
    float* __restrict__ out2) {
  int t = blockIdx.x * 256 + threadIdx.x;
  constexpr int N = cB * cK * cA * cC;
  if (t >= N) return;
  int e = t % (cA * cC);
  int bk = t / (cA * cC);
  int b = bk / cK;
  int g = idx[bk];
  out2[t] = boxes[((size_t)(b * cG + g)) * (cA * cC) + e];
}

// ---------------------------------------------------------------------------
// Kernel 3: gather sel_feat [B*K, D] as BF16 from feature [B, D, G] (f32).
// Reads: 64 lanes hit scattered g's within ONE feature row (line reuse);
// writes: transposed through padded LDS tile -> coalesced packed-bf16 pairs.
// grid: (K/64, D/64, B), 256 threads.
// ---------------------------------------------------------------------------
__global__ __launch_bounds__(256) void gather_feat_kernel(
    const float* __restrict__ feature, const int* __restrict__ idx,
    unsigned short* __restrict__ selfeat) {
  const int kc = blockIdx.x, dc = blockIdx.y, b = blockIdx.z;
  const int lane = threadIdx.x & 63;
  const int grp = threadIdx.x >> 6;  // 0..3
  __shared__ int sidx[64];
  __shared__ float tile[64][65];  // [d][k], pad +1 breaks transpose conflicts
  if (threadIdx.x < 64) sidx[threadIdx.x] = idx[b * cK + kc * 64 + threadIdx.x];
  __syncthreads();

  const size_t fbase = (size_t)b * cD * cG + (size_t)(dc * 64) * cG;
  const int g = sidx[lane];
  for (int dd = grp; dd < 64; dd += 4) {
    tile[dd][lane] = feature[fbase + (size_t)dd * cG + g];
  }
  __syncthreads();

  // write rows kk (selected index) x 64 d's as 32 packed uints
  const size_t obase = ((size_t)(b * cK + kc * 64)) * cD + dc * 64;
  for (int i = threadIdx.x; i < 64 * 32; i += 256) {
    const int kk = i >> 5;
    const int p = i & 31;
    unsigned v = packbf(tile[2 * p][kk], tile[2 * p + 1][kk]);
    *(unsigned*)(selfeat + obase + (size_t)kk * cD + 2 * p) = v;
  }
}

// ---------------------------------------------------------------------------
// Kernel 3b: W_vs [1024,512] f32 -> Wt [512,1024] bf16 (transposed).
// grid (8, 16) = (N/64, K/64), 256 threads, LDS 64x65 f32 tile.
// ---------------------------------------------------------------------------
__global__ __launch_bounds__(256) void wvs_transpose_kernel(
    const float* __restrict__ W, unsigned short* __restrict__ Wt) {
  const int n0 = blockIdx.x * 64;
  const int k0 = blockIdx.y * 64;
  const int tid = threadIdx.x;
  __shared__ float tile[64][65];  // [k][n]

  for (int i = tid; i < 1024; i += 256) {  // 1024 float4 units
    const int kk = i >> 4;
    const int c4 = (i & 15) * 4;
    const float4 v = *(const float4*)(W + (size_t)(k0 + kk) * cH + n0 + c4);
    tile[kk][c4 + 0] = v.x;
    tile[kk][c4 + 1] = v.y;
    tile[kk][c4 + 2] = v.z;
    tile[kk][c4 + 3] = v.w;
  }
  __syncthreads();

  for (int j = tid; j < 64 * 32; j += 256) {
    const int nn = j >> 5;
    const int p = j & 31;
    unsigned v = packbf(tile[2 * p][nn], tile[2 * p + 1][nn]);
    *(unsigned*)(Wt + (size_t)(n0 + nn) * cD + k0 + 2 * p) = v;
  }
}

// ---------------------------------------------------------------------------
// Kernel 4: BF16 MFMA GEMM for linear_feature.
// C[m, n] = sum_k A[m,k] * Wt[n,k] + b_vs[n], A=[4096,1024] bf16 (selfeat),
// Wt=[512,1024] bf16. Output packed: row m -> out[b=m>>7][m&127][n].
// Block = 256 thr (4 waves, 2x2), tile 128x128, BK=32.
// Wave (wr,wc) owns 64x64; 4x4 frags of mfma_f32_16x16x32_bf16.
// LDS [128][40] bf16 (pad 32->40: uniform bank load for b128 reads/writes).
// ---------------------------------------------------------------------------
__global__ __launch_bounds__(256) void gemm1_mfma_kernel(
    const unsigned short* __restrict__ A, const unsigned short* __restrict__ Wt,
    const float* __restrict__ bias, float* __restrict__ out) {
  const int bm = blockIdx.x;  // 32 (= batch)
  const int bn = blockIdx.y;  // 4
  const int tid = threadIdx.x;
  const int wid = tid >> 6;
  const int lane = tid & 63;
  const int wr = wid >> 1, wc = wid & 1;
  const int lr = lane & 15, lg = lane >> 4;

  __shared__ unsigned short As[128][40];
  __shared__ unsigned short Bs[128][40];

  f32x4 acc[4][4];
#pragma unroll
  for (int i = 0; i < 4; ++i)
#pragma unroll
    for (int j = 0; j < 4; ++j) acc[i][j] = {0.f, 0.f, 0.f, 0.f};

  const unsigned short* Abase = A + (size_t)bm * 128 * cD;
  const unsigned short* Bbase = Wt + (size_t)bn * 128 * cD;

  for (int kt = 0; kt < cD / 32; ++kt) {
#pragma unroll
    for (int h = 0; h < 2; ++h) {
      const int s = tid + h * 256;
      const int row = s >> 2;
      const int c16 = s & 3;
      const u16x8 va =
          *(const u16x8*)(Abase + (size_t)row * cD + kt * 32 + c16 * 8);
      *(u16x8*)&As[row][c16 * 8] = va;
      const u16x8 vb =
          *(const u16x8*)(Bbase + (size_t)row * cD + kt * 32 + c16 * 8);
      *(u16x8*)&Bs[row][c16 * 8] = vb;
    }
    __syncthreads();

    bf16x8 af[4], bf[4];
#pragma unroll
    for (int fr = 0; fr < 4; ++fr)
      af[fr] = *(const bf16x8*)&As[wr * 64 + fr * 16 + lr][lg * 8];
#pragma unroll
    for (int fc = 0; fc < 4; ++fc)
      bf[fc] = *(const bf16x8*)&Bs[wc * 64 + fc * 16 + lr][lg * 8];

#pragma unroll
    for (int fr = 0; fr < 4; ++fr)
#pragma unroll
      for (int fc = 0; fc < 4; ++fc)
        acc[fr][fc] = __builtin_amdgcn_mfma_f32_16x16x32_bf16(
            af[fr], bf[fc], acc[fr][fc], 0, 0, 0);
    __syncthreads();
  }

  // epilogue: bias + packed-row store
  float biasv[4];
#pragma unroll
  for (int fc = 0; fc < 4; ++fc)
    biasv[fc] = bias[bn * 128 + wc * 64 + fc * 16 + lr];

#pragma unroll
  for (int fr = 0; fr < 4; ++fr) {
#pragma unroll
    for (int fc = 0; fc < 4; ++fc) {
      const int col = bn * 128 + wc * 64 + fc * 16 + lr;
#pragma unroll
      for (int j = 0; j < 4; ++j) {
        const int row = bm * 128 + wr * 64 + fr * 16 + lg * 4 + j;
        const int bb = row >> 7;
        const int rr = row & 127;
        out[(size_t)bb * (ROWS_OUT * cH) + (size_t)rr * cH + col] =
            acc[fr][fc][j] + biasv[fc];
      }
    }
  }
}

// ---------------------------------------------------------------------------
// Kernel 5: f32 tiled GEMM (text path, small) with fused bias + row remap.
// ---------------------------------------------------------------------------
__global__ __launch_bounds__(256) void gemm_kernel(
    const float* __restrict__ Ap, const float* __restrict__ Bw,
    const float* __restrict__ bias, float* __restrict__ out, int Kd, int rpb,
    int row_off) {
  const int bm = blockIdx.x, bn = blockIdx.y;
  const int tid = threadIdx.x;
  __shared__ float As[16][68];
  __shared__ float Bs[16][64];

  const int tr = tid >> 4, tc = tid & 15;
  float acc[4][4] = {};

  const int a_m = tid >> 2;
  const int a_dk = (tid & 3) * 4;
  const int b_dk = tid >> 4;
  const int b_n = (tid & 15) * 4;

  const int nsteps = Kd >> 4;
  for (int kt = 0; kt < nsteps; ++kt) {
    const float4 av = *(const float4*)(Ap + (size_t)(bm * 64 + a_m) * Kd +
                                       kt * 16 + a_dk);
    As[a_dk + 0][a_m] = av.x;
    As[a_dk + 1][a_m] = av.y;
    As[a_dk + 2][a_m] = av.z;
    As[a_dk + 3][a_m] = av.w;
    const float4 bv = *(const float4*)(Bw + (size_t)(kt * 16 + b_dk) * cH +
                                       bn * 64 + b_n);
    *(float4*)&Bs[b_dk][b_n] = bv;
    __syncthreads();

#pragma unroll
    for (int dk = 0; dk < 16; ++dk) {
      const float4 a4 = *(const float4*)&As[dk][tr * 4];
      const float4 b4 = *(const float4*)&Bs[dk][tc * 4];
      acc[0][0] += a4.x * b4.x; acc[0][1] += a4.x * b4.y;
      acc[0][2] += a4.x * b4.z; acc[0][3] += a4.x * b4.w;
      acc[1][0] += a4.y * b4.x; acc[1][1] += a4.y * b4.y;
      acc[1][2] += a4.y * b4.z; acc[1][3] += a4.y * b4.w;
      acc[2][0] += a4.z * b4.x; acc[2][1] += a4.z * b4.y;
      acc[2][2] += a4.z * b4.z; acc[2][3] += a4.z * b4.w;
      acc[3][0] += a4.w * b4.x; acc[3][1] += a4.w * b4.y;
      acc[3][2] += a4.w * b4.z; acc[3][3] += a4.w * b4.w;
    }
    __syncthreads();
  }

  const int col = bn * 64 + tc * 4;
  const float4 bias4 = *(const float4*)(bias + col);
#pragma unroll
  for (int i = 0; i < 4; ++i) {
    const int row = bm * 64 + tr * 4 + i;
    const int bb = row / rpb;
    const int rr = row - bb * rpb;
    float4 v;
    v.x = acc[i][0] + bias4.x;
    v.y = acc[i][1] + bias4.y;
    v.z = acc[i][2] + bias4.z;
    v.w = acc[i][3] + bias4.w;
    *(float4*)(out + (size_t)bb * (ROWS_OUT * cH) +
               (size_t)(row_off + rr) * cH + col) = v;
  }
}

// ---------------------------------------------------------------------------
extern "C" void kernel_launch(void* const* d_in, const int* in_sizes, int n_in,
                              void* d_out, int out_size, void* d_ws,
                              size_t ws_size, hipStream_t stream) {
  const float* boxes = (const float*)d_in[0];
  const float* feature = (const float*)d_in[1];
  const float* text = (const float*)d_in[2];
  const float* W_vs = (const float*)d_in[3];
  const float* b_vs = (const float*)d_in[4];
  const float* W_tx = (const float*)d_in[5];
  const float* b_tx = (const float*)d_in[6];

  float* out = (float*)d_out;                           // [B, 148, 512]
  float* out_boxes = out + (size_t)cB * ROWS_OUT * cH;  // [B, K, 3, 6]

  // workspace: idx (16KB) | selfeat bf16 [4096,1024] (8.39MB) | Wt bf16 (1MB)
  int* idx = (int*)d_ws;
  unsigned short* selfeat = (unsigned short*)((char*)d_ws + 16384);
  unsigned short* Wt =
      (unsigned short*)((char*)d_ws + 16384 + (size_t)cB * cK * cD * 2);

  topk_kernel<<<cB, 256, 0, stream>>>(boxes, idx);

  {
    dim3 grid(cH / 64, cD / 64);
    wvs_transpose_kernel<<<grid, 256, 0, stream>>>(W_vs, Wt);
  }

  {
    constexpr int N = cB * cK * cA * cC;
    gather_boxes_kernel<<<(N + 255) / 256, 256, 0, stream>>>(boxes, idx,
                                                             out_boxes);
  }

  {
    dim3 grid(cK / 64, cD / 64, cB);
    gather_feat_kernel<<<grid, 256, 0, stream>>>(feature, idx, selfeat);
  }

  {
    dim3 grid((cB * cK) / 128, cH / 128);
    gemm1_mfma_kernel<<<grid, 256, 0, stream>>>(selfeat, Wt, b_vs, out);
  }

  {
    dim3 grid((cB * cL) / 64, cH / 64);
    gemm_kernel<<<grid, 256, 0, stream>>>(text, W_tx, b_tx, out, cH, cL, cK);
  }
}

// Round 4
// 82.178 us; speedup vs baseline: 5.7003x; 1.6251x over previous
//
#include <hip/hip_runtime.h>
#include <cstddef>

// Problem constants (fixed by the benchmark)
namespace {
constexpr int cB = 32;      // batch
constexpr int cG = 2704;    // grid cells (52*52)
constexpr int cA = 3;       // anchors
constexpr int cC = 6;       // channels per box
constexpr int cD = 1024;    // feature depth
constexpr int cL = 20;      // text tokens
constexpr int cH = 512;     // hidden
constexpr int cK = 128;     // select_num (scalar input, fixed = 128)
constexpr int ROWS_OUT = cK + cL;  // 148
constexpr int CHUNK = (cG + 255) / 256;  // 11 cells per thread
}

using u16x8 = __attribute__((ext_vector_type(8))) unsigned short;
using f32x4 = __attribute__((ext_vector_type(4))) float;
using bf16x8 = __attribute__((ext_vector_type(8))) short;

static __device__ __forceinline__ unsigned short f2bf(float f) {
  unsigned u = __float_as_uint(f);
  unsigned rounding = 0x7fffu + ((u >> 16) & 1u);
  return (unsigned short)((u + rounding) >> 16);
}
static __device__ __forceinline__ unsigned packbf(float lo, float hi) {
  return (unsigned)f2bf(lo) | ((unsigned)f2bf(hi) << 16);
}

// ---------------------------------------------------------------------------
// Kernel 1 "front": blocks [0,32): per-batch top-K radix select (wave-shuffle
// scans, ~23 barriers total) + fused box gather. Blocks [32,304): weight
// transposes to bf16 and text cast to bf16.
// ---------------------------------------------------------------------------
__global__ __launch_bounds__(256) void front_kernel(
    const float* __restrict__ boxes, const float* __restrict__ W_vs,
    const float* __restrict__ W_tx, const float* __restrict__ text,
    int* __restrict__ idx_out, float* __restrict__ out_boxes,
    unsigned short* __restrict__ Wt_vs, unsigned short* __restrict__ Wt_tx,
    unsigned short* __restrict__ text_bf) {
  __shared__ unsigned su[cG];
  __shared__ int hist[256];
  __shared__ int wsum[4];
  __shared__ int ssel[cK];
  __shared__ int s_rem;
  __shared__ unsigned s_prefix;
  __shared__ float tile[64][65];

  const int tid = threadIdx.x;
  const int lane = tid & 63;
  const int w4 = tid >> 6;

  if (blockIdx.x < cB) {
    // ---------------- top-K for batch b ----------------
    const int b = blockIdx.x;
    for (int g = tid; g < cG; g += 256) {
      const float* p = boxes + ((size_t)(b * cG + g) * cA) * cC + 4;
      float s = (p[0] + p[cC] + p[2 * cC]) * (1.0f / 3.0f);
      unsigned bits = __float_as_uint(s);
      su[g] = (bits & 0x80000000u) ? ~bits : (bits | 0x80000000u);
    }
    __syncthreads();

    int remaining = cK;
    unsigned prefix = 0;
    for (int pass = 0; pass < 4; ++pass) {
      const int shift = 24 - 8 * pass;
      hist[tid] = 0;
      __syncthreads();
      for (int g = tid; g < cG; g += 256) {
        unsigned u = su[g];
        if ((pass == 0) || ((u >> (shift + 8)) == (prefix >> (shift + 8))))
          atomicAdd(&hist[(u >> shift) & 255], 1);
      }
      __syncthreads();
      int h = hist[tid];
      int x = h;
#pragma unroll
      for (int d = 1; d < 64; d <<= 1) {
        int n = __shfl_up(x, d);
        if (lane >= d) x += n;
      }
      if (lane == 63) wsum[w4] = x;
      __syncthreads();
      int off = 0, T = 0;
#pragma unroll
      for (int w = 0; w < 4; ++w) {
        int s = wsum[w];
        T += s;
        if (w < w4) off += s;
      }
      const int pincl = x + off;
      const int pexcl = pincl - h;
      const int target = T - remaining;  // T >= remaining >= 1 invariant
      if (target >= pexcl && target < pincl) {
        s_prefix = prefix | ((unsigned)tid << shift);
        s_rem = remaining - (T - pincl);  // remaining - suffix(tid+1)
      }
      __syncthreads();
      remaining = s_rem;
      prefix = s_prefix;
      // next write to s_rem is 3 barriers away -> safe without extra barrier
    }

    // ---- stream compaction into LDS (ascending g; ties lowest-g first) ----
    const int g0 = tid * CHUNK;
    const int g1 = min(g0 + CHUNK, cG);
    int cgt = 0, ceq = 0;
    for (int g = g0; g < g1; ++g) {
      unsigned u = su[g];
      cgt += (u > prefix);
      ceq += (u == prefix);
    }
    int packed = (cgt << 16) | ceq;
    int x = packed;
#pragma unroll
    for (int d = 1; d < 64; d <<= 1) {
      int n = __shfl_up(x, d);
      if (lane >= d) x += n;
    }
    if (lane == 63) wsum[w4] = x;
    __syncthreads();
    int off = 0;
#pragma unroll
    for (int w = 0; w < 4; ++w)
      if (w < w4) off += wsum[w];
    const int excl = x + off - packed;
    int gt_before = excl >> 16;
    int eq_before = excl & 0xffff;

    for (int g = g0; g < g1; ++g) {
      unsigned u = su[g];
      if (u > prefix) {
        ssel[gt_before + min(eq_before, remaining)] = g;
        ++gt_before;
      } else if (u == prefix) {
        if (eq_before < remaining) ssel[gt_before + eq_before] = g;
        ++eq_before;
      }
    }
    __syncthreads();

    // ---- write indices + fused box gather ----
    if (tid < cK) idx_out[b * cK + tid] = ssel[tid];
    for (int t2 = tid; t2 < cK * (cA * cC); t2 += 256) {
      const int k = t2 / 18;
      const int e = t2 - k * 18;
      out_boxes[(size_t)(b * cK + k) * 18 + e] =
          boxes[((size_t)(b * cG) + ssel[k]) * 18 + e];
    }
  } else {
    // ---------------- prep: transposes + casts ----------------
    const int t = blockIdx.x - cB;
    if (t < 128) {
      // W_vs [1024,512] f32 -> Wt_vs [512][1024] bf16
      const int k0 = (t >> 3) * 64, n0 = (t & 7) * 64;
      for (int i = tid; i < 1024; i += 256) {
        const int kk = i >> 4, c4 = (i & 15) * 4;
        const float4 v =
            *(const float4*)(W_vs + (size_t)(k0 + kk) * cH + n0 + c4);
        tile[kk][c4 + 0] = v.x;
        tile[kk][c4 + 1] = v.y;
        tile[kk][c4 + 2] = v.z;
        tile[kk][c4 + 3] = v.w;
      }
      __syncthreads();
      for (int j = tid; j < 2048; j += 256) {
        const int nn = j >> 5, p = j & 31;
        unsigned v = packbf(tile[2 * p][nn], tile[2 * p + 1][nn]);
        *(unsigned*)(Wt_vs + (size_t)(n0 + nn) * cD + k0 + 2 * p) = v;
      }
    } else if (t < 192) {
      // W_tx [512,512] f32 -> Wt_tx [512][512] bf16
      const int t2 = t - 128;
      const int k0 = (t2 >> 3) * 64, n0 = (t2 & 7) * 64;
      for (int i = tid; i < 1024; i += 256) {
        const int kk = i >> 4, c4 = (i & 15) * 4;
        const float4 v =
            *(const float4*)(W_tx + (size_t)(k0 + kk) * cH + n0 + c4);
        tile[kk][c4 + 0] = v.x;
        tile[kk][c4 + 1] = v.y;
        tile[kk][c4 + 2] = v.z;
        tile[kk][c4 + 3] = v.w;
      }
      __syncthreads();
      for (int j = tid; j < 2048; j += 256) {
        const int nn = j >> 5, p = j & 31;
        unsigned v = packbf(tile[2 * p][nn], tile[2 * p + 1][nn]);
        *(unsigned*)(Wt_tx + (size_t)(n0 + nn) * cH + k0 + 2 * p) = v;
      }
    } else {
      // text [640,512] f32 -> bf16 (straight cast, coalesced)
      const int t3 = t - 192;
      const size_t base = (size_t)t3 * 4096;
      for (int i = tid; i < 1024; i += 256) {
        const float4 v = *(const float4*)(text + base + (size_t)i * 4);
        uint2 pv;
        pv.x = packbf(v.x, v.y);
        pv.y = packbf(v.z, v.w);
        *(uint2*)(text_bf + base + (size_t)i * 4) = pv;
      }
    }
  }
}

// ---------------------------------------------------------------------------
// Kernel 2: gather sel_feat [B*K, D] as BF16 from feature [B, D, G] (f32).
// Reads: 64 lanes hit scattered (sorted) g's within ONE d-row -> line reuse;
// writes: transposed through padded LDS tile -> coalesced packed-bf16.
// grid: (K/64, D/64, B), 256 threads. HBM-fetch-bound (~270 MB).
// ---------------------------------------------------------------------------
__global__ __launch_bounds__(256) void gather_feat_kernel(
    const float* __restrict__ feature, const int* __restrict__ idx,
    unsigned short* __restrict__ selfeat) {
  const int kc = blockIdx.x, dc = blockIdx.y, b = blockIdx.z;
  const int lane = threadIdx.x & 63;
  const int grp = threadIdx.x >> 6;
  __shared__ int sidx[64];
  __shared__ float tile[64][65];
  if (threadIdx.x < 64) sidx[threadIdx.x] = idx[b * cK + kc * 64 + threadIdx.x];
  __syncthreads();

  const size_t fbase = (size_t)b * cD * cG + (size_t)(dc * 64) * cG;
  const int g = sidx[lane];
  for (int dd = grp; dd < 64; dd += 4) {
    tile[dd][lane] = feature[fbase + (size_t)dd * cG + g];
  }
  __syncthreads();

  const size_t obase = ((size_t)(b * cK + kc * 64)) * cD + dc * 64;
  for (int i = threadIdx.x; i < 64 * 32; i += 256) {
    const int kk = i >> 5;
    const int p = i & 31;
    unsigned v = packbf(tile[2 * p][kk], tile[2 * p + 1][kk]);
    *(unsigned*)(selfeat + obase + (size_t)kk * cD + 2 * p) = v;
  }
}

// ---------------------------------------------------------------------------
// Kernel 3: merged BF16 MFMA GEMMs (feature + text) with 2-deep register
// prefetch + double-buffered LDS (1 barrier / K-step).
// C[m,n] = sum_k A[m,k]*Bt[n,k] + bias[n]; packed-row epilogue.
// Tile 128x128, 4 waves (2x2), BK=32, LDS pitch 40 shorts (80B, odd x16B ->
// conflict-free b128 phases).
// ---------------------------------------------------------------------------
template <int KD>
__device__ __forceinline__ void mfma_gemm_body(
    const unsigned short* __restrict__ A, const unsigned short* __restrict__ Bt,
    const float* __restrict__ bias, float* __restrict__ out, int bm, int bn,
    int rpb, int row_off, unsigned short (*As)[128][40],
    unsigned short (*Bs)[128][40]) {
  constexpr int NT = KD / 32;  // 32 or 16 (even)
  const int tid = threadIdx.x;
  const int wid = tid >> 6, lane = tid & 63;
  const int wr = wid >> 1, wc = wid & 1;
  const int lr = lane & 15, lg = lane >> 4;

  const int srow = tid >> 2;       // 0..63
  const int sc = (tid & 3) * 8;    // bf16 col: 0,8,16,24

  const unsigned short* pA0 = A + (size_t)(bm * 128 + srow) * KD + sc;
  const unsigned short* pA1 = pA0 + (size_t)64 * KD;
  const unsigned short* pB0 = Bt + (size_t)(bn * 128 + srow) * KD + sc;
  const unsigned short* pB1 = pB0 + (size_t)64 * KD;

  f32x4 acc[4][4];
#pragma unroll
  for (int i = 0; i < 4; ++i)
#pragma unroll
    for (int j = 0; j < 4; ++j) acc[i][j] = {0.f, 0.f, 0.f, 0.f};

  u16x8 xa0, xa1, xb0, xb1;  // prefetch set X (even tiles)
  u16x8 ya0, ya1, yb0, yb1;  // prefetch set Y (odd tiles)

#define LOAD_X(kt)                           \
  xa0 = *(const u16x8*)(pA0 + (kt) * 32);    \
  xa1 = *(const u16x8*)(pA1 + (kt) * 32);    \
  xb0 = *(const u16x8*)(pB0 + (kt) * 32);    \
  xb1 = *(const u16x8*)(pB1 + (kt) * 32);
#define LOAD_Y(kt)                           \
  ya0 = *(const u16x8*)(pA0 + (kt) * 32);    \
  ya1 = *(const u16x8*)(pA1 + (kt) * 32);    \
  yb0 = *(const u16x8*)(pB0 + (kt) * 32);    \
  yb1 = *(const u16x8*)(pB1 + (kt) * 32);
#define STORE_X(buf)                         \
  *(u16x8*)&As[buf][srow][sc] = xa0;         \
  *(u16x8*)&As[buf][srow + 64][sc] = xa1;    \
  *(u16x8*)&Bs[buf][srow][sc] = xb0;         \
  *(u16x8*)&Bs[buf][srow + 64][sc] = xb1;
#define STORE_Y(buf)                         \
  *(u16x8*)&As[buf][srow][sc] = ya0;         \
  *(u16x8*)&As[buf][srow + 64][sc] = ya1;    \
  *(u16x8*)&Bs[buf][srow][sc] = yb0;         \
  *(u16x8*)&Bs[buf][srow + 64][sc] = yb1;
#define COMPUTE(buf)                                                        \
  {                                                                         \
    bf16x8 af[4], bfr[4];                                                   \
    _Pragma("unroll") for (int fr = 0; fr < 4; ++fr) af[fr] =               \
        *(const bf16x8*)&As[buf][wr * 64 + fr * 16 + lr][lg * 8];           \
    _Pragma("unroll") for (int fc = 0; fc < 4; ++fc) bfr[fc] =              \
        *(const bf16x8*)&Bs[buf][wc * 64 + fc * 16 + lr][lg * 8];           \
    _Pragma("unroll") for (int fr = 0; fr < 4; ++fr)                        \
        _Pragma("unroll") for (int fc = 0; fc < 4; ++fc) acc[fr][fc] =      \
            __builtin_amdgcn_mfma_f32_16x16x32_bf16(af[fr], bfr[fc],        \
                                                    acc[fr][fc], 0, 0, 0);  \
  }

  LOAD_X(0);
  LOAD_Y(1);
  STORE_X(0);
  __syncthreads();

  for (int t = 0; t < NT; t += 2) {
    // even half: compute tile t (buf0); Y holds t+1
    if (t + 2 < NT) LOAD_X(t + 2);
    COMPUTE(0);
    STORE_Y(1);
    __syncthreads();
    // odd half: compute tile t+1 (buf1); X holds t+2
    if (t + 3 < NT) LOAD_Y(t + 3);
    COMPUTE(1);
    if (t + 2 < NT) STORE_X(0);
    __syncthreads();
  }
#undef LOAD_X
#undef LOAD_Y
#undef STORE_X
#undef STORE_Y
#undef COMPUTE

  // epilogue: bias + packed-row store
  float biasv[4];
#pragma unroll
  for (int fc = 0; fc < 4; ++fc)
    biasv[fc] = bias[bn * 128 + wc * 64 + fc * 16 + lr];

#pragma unroll
  for (int fr = 0; fr < 4; ++fr) {
#pragma unroll
    for (int fc = 0; fc < 4; ++fc) {
      const int col = bn * 128 + wc * 64 + fc * 16 + lr;
#pragma unroll
      for (int j = 0; j < 4; ++j) {
        const int row = bm * 128 + wr * 64 + fr * 16 + lg * 4 + j;
        const int bb = row / rpb;
        const int rr = row - bb * rpb;
        out[(size_t)bb * (ROWS_OUT * cH) + (size_t)(row_off + rr) * cH + col] =
            acc[fr][fc][j] + biasv[fc];
      }
    }
  }
}

__global__ __launch_bounds__(256) void gemms_kernel(
    const unsigned short* __restrict__ selfeat,
    const unsigned short* __restrict__ Wt_vs,
    const unsigned short* __restrict__ text_bf,
    const unsigned short* __restrict__ Wt_tx,
    const float* __restrict__ b_vs, const float* __restrict__ b_tx,
    float* __restrict__ out) {
  __shared__ unsigned short As[2][128][40];
  __shared__ unsigned short Bs[2][128][40];
  const int blk = blockIdx.x;
  if (blk < 128) {
    // linear_feature: [4096,1024] @ Wt_vs[512,1024]^T -> rows [0,128)/batch
    mfma_gemm_body<1024>(selfeat, Wt_vs, b_vs, out, blk >> 2, blk & 3, 128, 0,
                         As, Bs);
  } else {
    // linear_text: [640,512] @ Wt_tx[512,512]^T -> rows [128,148)/batch
    const int t = blk - 128;  // 20 blocks: 5 x 4
    mfma_gemm_body<512>(text_bf, Wt_tx, b_tx, out, t >> 2, t & 3, cL, cK, As,
                        Bs);
  }
}

// ---------------------------------------------------------------------------
extern "C" void kernel_launch(void* const* d_in, const int* in_sizes, int n_in,
                              void* d_out, int out_size, void* d_ws,
                              size_t ws_size, hipStream_t stream) {
  const float* boxes = (const float*)d_in[0];
  const float* feature = (const float*)d_in[1];
  const float* text = (const float*)d_in[2];
  const float* W_vs = (const float*)d_in[3];
  const float* b_vs = (const float*)d_in[4];
  const float* W_tx = (const float*)d_in[5];
  const float* b_tx = (const float*)d_in[6];

  float* out = (float*)d_out;                           // [B, 148, 512]
  float* out_boxes = out + (size_t)cB * ROWS_OUT * cH;  // [B, K, 3, 6]

  // workspace layout (bytes):
  //   idx      @ 0        (16 KB)
  //   selfeat  @ 16384    [4096,1024] bf16 (8 MB)
  //   Wt_vs    @ 8404992  [512][1024] bf16 (1 MB)
  //   Wt_tx    @ 9453568  [512][512]  bf16 (512 KB)
  //   text_bf  @ 9977856  [640][512]  bf16 (640 KB)
  int* idx = (int*)d_ws;
  unsigned short* selfeat = (unsigned short*)((char*)d_ws + 16384);
  unsigned short* Wt_vs = (unsigned short*)((char*)d_ws + 8404992);
  unsigned short* Wt_tx = (unsigned short*)((char*)d_ws + 9453568);
  unsigned short* text_bf = (unsigned short*)((char*)d_ws + 9977856);

  // 1) top-K + box gather + weight/text prep (304 blocks)
  front_kernel<<<cB + 272, 256, 0, stream>>>(boxes, W_vs, W_tx, text, idx,
                                             out_boxes, Wt_vs, Wt_tx, text_bf);

  // 2) gather selected feature columns -> sel_feat bf16 [B*K, D]
  {
    dim3 grid(cK / 64, cD / 64, cB);
    gather_feat_kernel<<<grid, 256, 0, stream>>>(feature, idx, selfeat);
  }

  // 3) both GEMMs in one launch (128 + 20 blocks)
  gemms_kernel<<<148, 256, 0, stream>>>(selfeat, Wt_vs, text_bf, Wt_tx, b_vs,
                                        b_tx, out);
}

// Round 5
// 81.561 us; speedup vs baseline: 5.7433x; 1.0076x over previous
//
#include <hip/hip_runtime.h>
#include <cstddef>

// Problem constants (fixed by the benchmark)
namespace {
constexpr int cB = 32;      // batch
constexpr int cG = 2704;    // grid cells (52*52)
constexpr int cA = 3;       // anchors
constexpr int cC = 6;       // channels per box
constexpr int cD = 1024;    // feature depth
constexpr int cL = 20;      // text tokens
constexpr int cH = 512;     // hidden
constexpr int cK = 128;     // select_num (scalar input, fixed = 128)
constexpr int ROWS_OUT = cK + cL;  // 148
constexpr int CHUNK = (cG + 255) / 256;  // 11 cells per thread
}

using u16x8 = __attribute__((ext_vector_type(8))) unsigned short;
using f32x4 = __attribute__((ext_vector_type(4))) float;
using bf16x8 = __attribute__((ext_vector_type(8))) short;

static __device__ __forceinline__ unsigned short f2bf(float f) {
  unsigned u = __float_as_uint(f);
  unsigned rounding = 0x7fffu + ((u >> 16) & 1u);
  return (unsigned short)((u + rounding) >> 16);
}
static __device__ __forceinline__ unsigned packbf(float lo, float hi) {
  return (unsigned)f2bf(lo) | ((unsigned)f2bf(hi) << 16);
}

// ---------------------------------------------------------------------------
// Kernel 1 "front": blocks [0,32): per-batch top-K radix select (wave-shuffle
// scans) + fused box gather. Blocks [32,304): weight transposes to bf16 and
// text cast to bf16.
// ---------------------------------------------------------------------------
__global__ __launch_bounds__(256) void front_kernel(
    const float* __restrict__ boxes, const float* __restrict__ W_vs,
    const float* __restrict__ W_tx, const float* __restrict__ text,
    int* __restrict__ idx_out, float* __restrict__ out_boxes,
    unsigned short* __restrict__ Wt_vs, unsigned short* __restrict__ Wt_tx,
    unsigned short* __restrict__ text_bf) {
  __shared__ unsigned su[cG];
  __shared__ int hist[256];
  __shared__ int wsum[4];
  __shared__ int ssel[cK];
  __shared__ int s_rem;
  __shared__ unsigned s_prefix;
  __shared__ float tile[64][65];

  const int tid = threadIdx.x;
  const int lane = tid & 63;
  const int w4 = tid >> 6;

  if (blockIdx.x < cB) {
    // ---------------- top-K for batch b ----------------
    const int b = blockIdx.x;
    for (int g = tid; g < cG; g += 256) {
      const float* p = boxes + ((size_t)(b * cG + g) * cA) * cC + 4;
      float s = (p[0] + p[cC] + p[2 * cC]) * (1.0f / 3.0f);
      unsigned bits = __float_as_uint(s);
      su[g] = (bits & 0x80000000u) ? ~bits : (bits | 0x80000000u);
    }
    __syncthreads();

    int remaining = cK;
    unsigned prefix = 0;
    for (int pass = 0; pass < 4; ++pass) {
      const int shift = 24 - 8 * pass;
      hist[tid] = 0;
      __syncthreads();
      for (int g = tid; g < cG; g += 256) {
        unsigned u = su[g];
        if ((pass == 0) || ((u >> (shift + 8)) == (prefix >> (shift + 8))))
          atomicAdd(&hist[(u >> shift) & 255], 1);
      }
      __syncthreads();
      int h = hist[tid];
      int x = h;
#pragma unroll
      for (int d = 1; d < 64; d <<= 1) {
        int n = __shfl_up(x, d);
        if (lane >= d) x += n;
      }
      if (lane == 63) wsum[w4] = x;
      __syncthreads();
      int off = 0, T = 0;
#pragma unroll
      for (int w = 0; w < 4; ++w) {
        int s = wsum[w];
        T += s;
        if (w < w4) off += s;
      }
      const int pincl = x + off;
      const int pexcl = pincl - h;
      const int target = T - remaining;  // T >= remaining >= 1 invariant
      if (target >= pexcl && target < pincl) {
        s_prefix = prefix | ((unsigned)tid << shift);
        s_rem = remaining - (T - pincl);  // remaining - suffix(tid+1)
      }
      __syncthreads();
      remaining = s_rem;
      prefix = s_prefix;
      // next write to s_rem is 3 barriers away -> safe without extra barrier
    }

    // ---- stream compaction into LDS (ascending g; ties lowest-g first) ----
    const int g0 = tid * CHUNK;
    const int g1 = min(g0 + CHUNK, cG);
    int cgt = 0, ceq = 0;
    for (int g = g0; g < g1; ++g) {
      unsigned u = su[g];
      cgt += (u > prefix);
      ceq += (u == prefix);
    }
    int packed = (cgt << 16) | ceq;
    int x = packed;
#pragma unroll
    for (int d = 1; d < 64; d <<= 1) {
      int n = __shfl_up(x, d);
      if (lane >= d) x += n;
    }
    if (lane == 63) wsum[w4] = x;
    __syncthreads();
    int off = 0;
#pragma unroll
    for (int w = 0; w < 4; ++w)
      if (w < w4) off += wsum[w];
    const int excl = x + off - packed;
    int gt_before = excl >> 16;
    int eq_before = excl & 0xffff;

    for (int g = g0; g < g1; ++g) {
      unsigned u = su[g];
      if (u > prefix) {
        ssel[gt_before + min(eq_before, remaining)] = g;
        ++gt_before;
      } else if (u == prefix) {
        if (eq_before < remaining) ssel[gt_before + eq_before] = g;
        ++eq_before;
      }
    }
    __syncthreads();

    // ---- write indices + fused box gather ----
    if (tid < cK) idx_out[b * cK + tid] = ssel[tid];
    for (int t2 = tid; t2 < cK * (cA * cC); t2 += 256) {
      const int k = t2 / 18;
      const int e = t2 - k * 18;
      out_boxes[(size_t)(b * cK + k) * 18 + e] =
          boxes[((size_t)(b * cG) + ssel[k]) * 18 + e];
    }
  } else {
    // ---------------- prep: transposes + casts ----------------
    const int t = blockIdx.x - cB;
    if (t < 128) {
      // W_vs [1024,512] f32 -> Wt_vs [512][1024] bf16
      const int k0 = (t >> 3) * 64, n0 = (t & 7) * 64;
      for (int i = tid; i < 1024; i += 256) {
        const int kk = i >> 4, c4 = (i & 15) * 4;
        const float4 v =
            *(const float4*)(W_vs + (size_t)(k0 + kk) * cH + n0 + c4);
        tile[kk][c4 + 0] = v.x;
        tile[kk][c4 + 1] = v.y;
        tile[kk][c4 + 2] = v.z;
        tile[kk][c4 + 3] = v.w;
      }
      __syncthreads();
      for (int j = tid; j < 2048; j += 256) {
        const int nn = j >> 5, p = j & 31;
        unsigned v = packbf(tile[2 * p][nn], tile[2 * p + 1][nn]);
        *(unsigned*)(Wt_vs + (size_t)(n0 + nn) * cD + k0 + 2 * p) = v;
      }
    } else if (t < 192) {
      // W_tx [512,512] f32 -> Wt_tx [512][512] bf16
      const int t2 = t - 128;
      const int k0 = (t2 >> 3) * 64, n0 = (t2 & 7) * 64;
      for (int i = tid; i < 1024; i += 256) {
        const int kk = i >> 4, c4 = (i & 15) * 4;
        const float4 v =
            *(const float4*)(W_tx + (size_t)(k0 + kk) * cH + n0 + c4);
        tile[kk][c4 + 0] = v.x;
        tile[kk][c4 + 1] = v.y;
        tile[kk][c4 + 2] = v.z;
        tile[kk][c4 + 3] = v.w;
      }
      __syncthreads();
      for (int j = tid; j < 2048; j += 256) {
        const int nn = j >> 5, p = j & 31;
        unsigned v = packbf(tile[2 * p][nn], tile[2 * p + 1][nn]);
        *(unsigned*)(Wt_tx + (size_t)(n0 + nn) * cH + k0 + 2 * p) = v;
      }
    } else {
      // text [640,512] f32 -> bf16 (straight cast, coalesced)
      const int t3 = t - 192;
      const size_t base = (size_t)t3 * 4096;
      for (int i = tid; i < 1024; i += 256) {
        const float4 v = *(const float4*)(text + base + (size_t)i * 4);
        uint2 pv;
        pv.x = packbf(v.x, v.y);
        pv.y = packbf(v.z, v.w);
        *(uint2*)(text_bf + base + (size_t)i * 4) = pv;
      }
    }
  }
}

// ---------------------------------------------------------------------------
// Kernel 2: gather sel_feat [B*K, D] as BF16 from feature [B, D, G] (f32).
// 2048 blocks (64k x 32d tiles) -> 8 blocks/CU (32 waves/CU, max occupancy).
// Per lane: 8 scattered loads issued back-to-back into registers (8-deep
// vmem pipeline), then LDS transpose, then packed-bf16 uint2 writes.
// ---------------------------------------------------------------------------
__global__ __launch_bounds__(256) void gather_feat_kernel(
    const float* __restrict__ feature, const int* __restrict__ idx,
    unsigned short* __restrict__ selfeat) {
  const int kc = blockIdx.x;  // 0..1
  const int dc = blockIdx.y;  // 0..31
  const int b = blockIdx.z;   // 0..31
  const int tid = threadIdx.x;
  const int lane = tid & 63;
  const int grp = tid >> 6;
  __shared__ int sidx[64];
  __shared__ float tile[32][65];
  if (tid < 64) sidx[tid] = idx[b * cK + kc * 64 + tid];
  __syncthreads();

  const int g = sidx[lane];
  const float* fptr =
      feature + (size_t)b * cD * cG + (size_t)(dc * 32 + grp * 8) * cG + g;
  float f[8];
#pragma unroll
  for (int j = 0; j < 8; ++j) f[j] = fptr[(size_t)j * cG];
#pragma unroll
  for (int j = 0; j < 8; ++j) tile[grp * 8 + j][lane] = f[j];
  __syncthreads();

  // transpose-write: 64 k-rows x 32 d as 8B packed-bf16 per thread-iter
  const size_t obase = ((size_t)(b * cK + kc * 64)) * cD + dc * 32;
#pragma unroll
  for (int it = 0; it < 2; ++it) {
    const int i = tid + it * 256;
    const int kk = i >> 3;
    const int q = i & 7;
    uint2 pv;
    pv.x = packbf(tile[4 * q + 0][kk], tile[4 * q + 1][kk]);
    pv.y = packbf(tile[4 * q + 2][kk], tile[4 * q + 3][kk]);
    *(uint2*)(selfeat + obase + (size_t)kk * cD + 4 * q) = pv;
  }
}

// ---------------------------------------------------------------------------
// Kernel 3: merged BF16 MFMA GEMMs, 512 threads (8 waves = 2/SIMD for
// wave-level latency overlap), 2-deep register prefetch + double-buffered
// LDS (1 barrier / K-step). Tile 128x128, wave grid 2x4, wave tile 64x32.
// ---------------------------------------------------------------------------
template <int KD>
__device__ __forceinline__ void mfma_gemm_body(
    const unsigned short* __restrict__ A, const unsigned short* __restrict__ Bt,
    const float* __restrict__ bias, float* __restrict__ out, int bm, int bn,
    int rpb, int row_off, unsigned short (*As)[128][40],
    unsigned short (*Bs)[128][40]) {
  constexpr int NT = KD / 32;  // 32 or 16 (even)
  const int tid = threadIdx.x;
  const int wid = tid >> 6, lane = tid & 63;
  const int wr = wid >> 2, wc = wid & 3;  // 2 x 4 waves
  const int lr = lane & 15, lg = lane >> 4;

  const int srow = tid >> 2;     // 0..127
  const int sc = (tid & 3) * 8;  // bf16 col: 0,8,16,24

  const unsigned short* pA = A + (size_t)(bm * 128 + srow) * KD + sc;
  const unsigned short* pB = Bt + (size_t)(bn * 128 + srow) * KD + sc;

  f32x4 acc[4][2];
#pragma unroll
  for (int i = 0; i < 4; ++i)
#pragma unroll
    for (int j = 0; j < 2; ++j) acc[i][j] = {0.f, 0.f, 0.f, 0.f};

  u16x8 xa, xb;  // prefetch set X (even tiles)
  u16x8 ya, yb;  // prefetch set Y (odd tiles)

#define LOAD_X(kt)                      \
  xa = *(const u16x8*)(pA + (kt) * 32); \
  xb = *(const u16x8*)(pB + (kt) * 32);
#define LOAD_Y(kt)                      \
  ya = *(const u16x8*)(pA + (kt) * 32); \
  yb = *(const u16x8*)(pB + (kt) * 32);
#define STORE_X(buf)               \
  *(u16x8*)&As[buf][srow][sc] = xa; \
  *(u16x8*)&Bs[buf][srow][sc] = xb;
#define STORE_Y(buf)               \
  *(u16x8*)&As[buf][srow][sc] = ya; \
  *(u16x8*)&Bs[buf][srow][sc] = yb;
#define COMPUTE(buf)                                                        \
  {                                                                         \
    bf16x8 af[4], bfr[2];                                                   \
    _Pragma("unroll") for (int fr = 0; fr < 4; ++fr) af[fr] =               \
        *(const bf16x8*)&As[buf][wr * 64 + fr * 16 + lr][lg * 8];           \
    _Pragma("unroll") for (int fc = 0; fc < 2; ++fc) bfr[fc] =              \
        *(const bf16x8*)&Bs[buf][wc * 32 + fc * 16 + lr][lg * 8];           \
    _Pragma("unroll") for (int fr = 0; fr < 4; ++fr)                        \
        _Pragma("unroll") for (int fc = 0; fc < 2; ++fc) acc[fr][fc] =      \
            __builtin_amdgcn_mfma_f32_16x16x32_bf16(af[fr], bfr[fc],        \
                                                    acc[fr][fc], 0, 0, 0);  \
  }

  LOAD_X(0);
  LOAD_Y(1);
  STORE_X(0);
  __syncthreads();

  for (int t = 0; t < NT; t += 2) {
    if (t + 2 < NT) LOAD_X(t + 2);
    COMPUTE(0);
    STORE_Y(1);
    __syncthreads();
    if (t + 3 < NT) LOAD_Y(t + 3);
    COMPUTE(1);
    if (t + 2 < NT) STORE_X(0);
    __syncthreads();
  }
#undef LOAD_X
#undef LOAD_Y
#undef STORE_X
#undef STORE_Y
#undef COMPUTE

  // epilogue: bias + packed-row store
  float biasv[2];
#pragma unroll
  for (int fc = 0; fc < 2; ++fc)
    biasv[fc] = bias[bn * 128 + wc * 32 + fc * 16 + lr];

#pragma unroll
  for (int fr = 0; fr < 4; ++fr) {
#pragma unroll
    for (int fc = 0; fc < 2; ++fc) {
      const int col = bn * 128 + wc * 32 + fc * 16 + lr;
#pragma unroll
      for (int j = 0; j < 4; ++j) {
        const int row = bm * 128 + wr * 64 + fr * 16 + lg * 4 + j;
        const int bb = row / rpb;
        const int rr = row - bb * rpb;
        out[(size_t)bb * (ROWS_OUT * cH) + (size_t)(row_off + rr) * cH + col] =
            acc[fr][fc][j] + biasv[fc];
      }
    }
  }
}

__global__ __launch_bounds__(512) void gemms_kernel(
    const unsigned short* __restrict__ selfeat,
    const unsigned short* __restrict__ Wt_vs,
    const unsigned short* __restrict__ text_bf,
    const unsigned short* __restrict__ Wt_tx, const float* __restrict__ b_vs,
    const float* __restrict__ b_tx, float* __restrict__ out) {
  __shared__ unsigned short As[2][128][40];
  __shared__ unsigned short Bs[2][128][40];
  const int blk = blockIdx.x;
  if (blk < 128) {
    // XCD-chunked swizzle: hw blocks with blk%8==x handle bm in [4x,4x+4),
    // all bn -> A-panels fetched once per XCD L2 instead of 4x from HBM.
    const int w = ((blk & 7) << 4) | (blk >> 3);
    mfma_gemm_body<1024>(selfeat, Wt_vs, b_vs, out, w >> 2, w & 3, 128, 0, As,
                         Bs);
  } else {
    // linear_text: [640,512] @ Wt_tx[512,512]^T -> rows [128,148)/batch
    const int t = blk - 128;  // 20 blocks: 5 x 4
    mfma_gemm_body<512>(text_bf, Wt_tx, b_tx, out, t >> 2, t & 3, cL, cK, As,
                        Bs);
  }
}

// ---------------------------------------------------------------------------
extern "C" void kernel_launch(void* const* d_in, const int* in_sizes, int n_in,
                              void* d_out, int out_size, void* d_ws,
                              size_t ws_size, hipStream_t stream) {
  const float* boxes = (const float*)d_in[0];
  const float* feature = (const float*)d_in[1];
  const float* text = (const float*)d_in[2];
  const float* W_vs = (const float*)d_in[3];
  const float* b_vs = (const float*)d_in[4];
  const float* W_tx = (const float*)d_in[5];
  const float* b_tx = (const float*)d_in[6];

  float* out = (float*)d_out;                           // [B, 148, 512]
  float* out_boxes = out + (size_t)cB * ROWS_OUT * cH;  // [B, K, 3, 6]

  // workspace layout (bytes):
  //   idx      @ 0        (16 KB)
  //   selfeat  @ 16384    [4096,1024] bf16 (8 MB)
  //   Wt_vs    @ 8404992  [512][1024] bf16 (1 MB)
  //   Wt_tx    @ 9453568  [512][512]  bf16 (512 KB)
  //   text_bf  @ 9977856  [640][512]  bf16 (640 KB)
  int* idx = (int*)d_ws;
  unsigned short* selfeat = (unsigned short*)((char*)d_ws + 16384);
  unsigned short* Wt_vs = (unsigned short*)((char*)d_ws + 8404992);
  unsigned short* Wt_tx = (unsigned short*)((char*)d_ws + 9453568);
  unsigned short* text_bf = (unsigned short*)((char*)d_ws + 9977856);

  // 1) top-K + box gather + weight/text prep (304 blocks)
  front_kernel<<<cB + 272, 256, 0, stream>>>(boxes, W_vs, W_tx, text, idx,
                                             out_boxes, Wt_vs, Wt_tx, text_bf);

  // 2) gather selected feature columns -> sel_feat bf16 [B*K, D]
  {
    dim3 grid(2, 32, 32);
    gather_feat_kernel<<<grid, 256, 0, stream>>>(feature, idx, selfeat);
  }

  // 3) both GEMMs in one launch (128 + 20 blocks, 512 threads)
  gemms_kernel<<<148, 512, 0, stream>>>(selfeat, Wt_vs, text_bf, Wt_tx, b_vs,
                                        b_tx, out);
}

// Round 6
// 81.321 us; speedup vs baseline: 5.7603x; 1.0030x over previous
//
#include <hip/hip_runtime.h>
#include <cstddef>

// Problem constants (fixed by the benchmark)
namespace {
constexpr int cB = 32;      // batch
constexpr int cG = 2704;    // grid cells (52*52)
constexpr int cA = 3;       // anchors
constexpr int cC = 6;       // channels per box
constexpr int cD = 1024;    // feature depth
constexpr int cL = 20;      // text tokens
constexpr int cH = 512;     // hidden
constexpr int cK = 128;     // select_num (scalar input, fixed = 128)
constexpr int ROWS_OUT = cK + cL;  // 148
constexpr int FTHREADS = 512;            // front block size
constexpr int CHUNK = (cG + FTHREADS - 1) / FTHREADS;  // 6 cells per thread
}

using u16x8 = __attribute__((ext_vector_type(8))) unsigned short;
using f32x4 = __attribute__((ext_vector_type(4))) float;
using bf16x8 = __attribute__((ext_vector_type(8))) short;

static __device__ __forceinline__ unsigned short f2bf(float f) {
  unsigned u = __float_as_uint(f);
  unsigned rounding = 0x7fffu + ((u >> 16) & 1u);
  return (unsigned short)((u + rounding) >> 16);
}
static __device__ __forceinline__ unsigned packbf(float lo, float hi) {
  return (unsigned)f2bf(lo) | ((unsigned)f2bf(hi) << 16);
}

// ---------------------------------------------------------------------------
// Kernel 1 "front" (512 thr): blocks [0,32): per-batch top-K radix select
// (wave-shuffle scans) + fused box gather. Blocks [32,304): weight transposes
// to bf16 and text cast to bf16.
// ---------------------------------------------------------------------------
__global__ __launch_bounds__(FTHREADS) void front_kernel(
    const float* __restrict__ boxes, const float* __restrict__ W_vs,
    const float* __restrict__ W_tx, const float* __restrict__ text,
    int* __restrict__ idx_out, float* __restrict__ out_boxes,
    unsigned short* __restrict__ Wt_vs, unsigned short* __restrict__ Wt_tx,
    unsigned short* __restrict__ text_bf) {
  __shared__ unsigned su[cG];
  __shared__ int hist[256];
  __shared__ int wsum[8];
  __shared__ int ssel[cK];
  __shared__ int s_rem;
  __shared__ unsigned s_prefix;
  __shared__ float tile[64][65];

  const int tid = threadIdx.x;
  const int lane = tid & 63;
  const int wv = tid >> 6;  // 0..7

  if (blockIdx.x < cB) {
    // ---------------- top-K for batch b ----------------
    const int b = blockIdx.x;
    for (int g = tid; g < cG; g += FTHREADS) {
      const float* p = boxes + ((size_t)(b * cG + g) * cA) * cC + 4;
      float s = (p[0] + p[cC] + p[2 * cC]) * (1.0f / 3.0f);
      unsigned bits = __float_as_uint(s);
      su[g] = (bits & 0x80000000u) ? ~bits : (bits | 0x80000000u);
    }
    __syncthreads();

    int remaining = cK;
    unsigned prefix = 0;
    for (int pass = 0; pass < 4; ++pass) {
      const int shift = 24 - 8 * pass;
      if (tid < 256) hist[tid] = 0;
      __syncthreads();
      for (int g = tid; g < cG; g += FTHREADS) {
        unsigned u = su[g];
        if ((pass == 0) || ((u >> (shift + 8)) == (prefix >> (shift + 8))))
          atomicAdd(&hist[(u >> shift) & 255], 1);
      }
      __syncthreads();
      if (tid < 256) {
        int h = hist[tid];
        int x = h;
#pragma unroll
        for (int d = 1; d < 64; d <<= 1) {
          int n = __shfl_up(x, d);
          if (lane >= d) x += n;
        }
        if (lane == 63) wsum[wv] = x;
        __syncthreads();
        int off = 0, T = 0;
#pragma unroll
        for (int w = 0; w < 4; ++w) {
          int s = wsum[w];
          T += s;
          if (w < wv) off += s;
        }
        const int pincl = x + off;
        const int pexcl = pincl - h;
        const int target = T - remaining;  // T >= remaining >= 1 invariant
        if (target >= pexcl && target < pincl) {
          s_prefix = prefix | ((unsigned)tid << shift);
          s_rem = remaining - (T - pincl);  // remaining - suffix(tid+1)
        }
      } else {
        __syncthreads();
      }
      __syncthreads();
      remaining = s_rem;
      prefix = s_prefix;
      // next write to s_rem is >=2 barriers after this read -> safe
    }

    // ---- stream compaction into LDS (ascending g; ties lowest-g first) ----
    const int g0 = tid * CHUNK;
    const int g1 = min(g0 + CHUNK, cG);
    int cgt = 0, ceq = 0;
    for (int g = g0; g < g1; ++g) {
      unsigned u = su[g];
      cgt += (u > prefix);
      ceq += (u == prefix);
    }
    int packed = (cgt << 16) | ceq;
    int x = packed;
#pragma unroll
    for (int d = 1; d < 64; d <<= 1) {
      int n = __shfl_up(x, d);
      if (lane >= d) x += n;
    }
    if (lane == 63) wsum[wv] = x;
    __syncthreads();
    int off = 0;
#pragma unroll
    for (int w = 0; w < 8; ++w)
      if (w < wv) off += wsum[w];
    const int excl = x + off - packed;
    int gt_before = excl >> 16;
    int eq_before = excl & 0xffff;

    for (int g = g0; g < g1; ++g) {
      unsigned u = su[g];
      if (u > prefix) {
        ssel[gt_before + min(eq_before, remaining)] = g;
        ++gt_before;
      } else if (u == prefix) {
        if (eq_before < remaining) ssel[gt_before + eq_before] = g;
        ++eq_before;
      }
    }
    __syncthreads();

    // ---- write indices + fused box gather ----
    if (tid < cK) idx_out[b * cK + tid] = ssel[tid];
    for (int t2 = tid; t2 < cK * (cA * cC); t2 += FTHREADS) {
      const int k = t2 / 18;
      const int e = t2 - k * 18;
      out_boxes[(size_t)(b * cK + k) * 18 + e] =
          boxes[((size_t)(b * cG) + ssel[k]) * 18 + e];
    }
  } else {
    // ---------------- prep: transposes + casts ----------------
    const int t = blockIdx.x - cB;
    if (t < 128) {
      // W_vs [1024,512] f32 -> Wt_vs [512][1024] bf16
      const int k0 = (t >> 3) * 64, n0 = (t & 7) * 64;
      for (int i = tid; i < 1024; i += FTHREADS) {
        const int kk = i >> 4, c4 = (i & 15) * 4;
        const float4 v =
            *(const float4*)(W_vs + (size_t)(k0 + kk) * cH + n0 + c4);
        tile[kk][c4 + 0] = v.x;
        tile[kk][c4 + 1] = v.y;
        tile[kk][c4 + 2] = v.z;
        tile[kk][c4 + 3] = v.w;
      }
      __syncthreads();
      for (int j = tid; j < 2048; j += FTHREADS) {
        const int nn = j >> 5, p = j & 31;
        unsigned v = packbf(tile[2 * p][nn], tile[2 * p + 1][nn]);
        *(unsigned*)(Wt_vs + (size_t)(n0 + nn) * cD + k0 + 2 * p) = v;
      }
    } else if (t < 192) {
      // W_tx [512,512] f32 -> Wt_tx [512][512] bf16
      const int t2 = t - 128;
      const int k0 = (t2 >> 3) * 64, n0 = (t2 & 7) * 64;
      for (int i = tid; i < 1024; i += FTHREADS) {
        const int kk = i >> 4, c4 = (i & 15) * 4;
        const float4 v =
            *(const float4*)(W_tx + (size_t)(k0 + kk) * cH + n0 + c4);
        tile[kk][c4 + 0] = v.x;
        tile[kk][c4 + 1] = v.y;
        tile[kk][c4 + 2] = v.z;
        tile[kk][c4 + 3] = v.w;
      }
      __syncthreads();
      for (int j = tid; j < 2048; j += FTHREADS) {
        const int nn = j >> 5, p = j & 31;
        unsigned v = packbf(tile[2 * p][nn], tile[2 * p + 1][nn]);
        *(unsigned*)(Wt_tx + (size_t)(n0 + nn) * cH + k0 + 2 * p) = v;
      }
    } else {
      // text [640,512] f32 -> bf16 (straight cast, coalesced)
      const int t3 = t - 192;
      const size_t base = (size_t)t3 * 4096;
      for (int i = tid; i < 1024; i += FTHREADS) {
        const float4 v = *(const float4*)(text + base + (size_t)i * 4);
        uint2 pv;
        pv.x = packbf(v.x, v.y);
        pv.y = packbf(v.z, v.w);
        *(uint2*)(text_bf + base + (size_t)i * 4) = pv;
      }
    }
  }
}

// ---------------------------------------------------------------------------
// Kernel 2: gather sel_feat [B*K, D] as BF16 from feature [B, D, G] (f32).
// 2048 blocks (64k x 32d tiles) -> 8 blocks/CU. Per lane: 8 scattered
// NON-TEMPORAL loads (one-touch data; avoid L2 line allocation / bigger
// fetch grain) issued back-to-back, then LDS transpose, packed-bf16 writes.
// ---------------------------------------------------------------------------
__global__ __launch_bounds__(256) void gather_feat_kernel(
    const float* __restrict__ feature, const int* __restrict__ idx,
    unsigned short* __restrict__ selfeat) {
  const int kc = blockIdx.x;  // 0..1
  const int dc = blockIdx.y;  // 0..31
  const int b = blockIdx.z;   // 0..31
  const int tid = threadIdx.x;
  const int lane = tid & 63;
  const int grp = tid >> 6;
  __shared__ int sidx[64];
  __shared__ float tile[32][65];
  if (tid < 64) sidx[tid] = idx[b * cK + kc * 64 + tid];
  __syncthreads();

  const int g = sidx[lane];
  const float* fptr =
      feature + (size_t)b * cD * cG + (size_t)(dc * 32 + grp * 8) * cG + g;
  float f[8];
#pragma unroll
  for (int j = 0; j < 8; ++j) f[j] = __builtin_nontemporal_load(fptr + (size_t)j * cG);
#pragma unroll
  for (int j = 0; j < 8; ++j) tile[grp * 8 + j][lane] = f[j];
  __syncthreads();

  // transpose-write: 64 k-rows x 32 d as 8B packed-bf16 per thread-iter
  const size_t obase = ((size_t)(b * cK + kc * 64)) * cD + dc * 32;
#pragma unroll
  for (int it = 0; it < 2; ++it) {
    const int i = tid + it * 256;
    const int kk = i >> 3;
    const int q = i & 7;
    uint2 pv;
    pv.x = packbf(tile[4 * q + 0][kk], tile[4 * q + 1][kk]);
    pv.y = packbf(tile[4 * q + 2][kk], tile[4 * q + 3][kk]);
    *(uint2*)(selfeat + obase + (size_t)kk * cD + 4 * q) = pv;
  }
}

// ---------------------------------------------------------------------------
// Kernel 3: merged BF16 MFMA GEMMs, 512 threads (8 waves = 2/SIMD),
// 2-deep register prefetch + double-buffered LDS (1 barrier / K-step).
// Tile 128x128, wave grid 2x4, wave tile 64x32.
// ---------------------------------------------------------------------------
template <int KD>
__device__ __forceinline__ void mfma_gemm_body(
    const unsigned short* __restrict__ A, const unsigned short* __restrict__ Bt,
    const float* __restrict__ bias, float* __restrict__ out, int bm, int bn,
    int rpb, int row_off, unsigned short (*As)[128][40],
    unsigned short (*Bs)[128][40]) {
  constexpr int NT = KD / 32;  // 32 or 16 (even)
  const int tid = threadIdx.x;
  const int wid = tid >> 6, lane = tid & 63;
  const int wr = wid >> 2, wc = wid & 3;  // 2 x 4 waves
  const int lr = lane & 15, lg = lane >> 4;

  const int srow = tid >> 2;     // 0..127
  const int sc = (tid & 3) * 8;  // bf16 col: 0,8,16,24

  const unsigned short* pA = A + (size_t)(bm * 128 + srow) * KD + sc;
  const unsigned short* pB = Bt + (size_t)(bn * 128 + srow) * KD + sc;

  f32x4 acc[4][2];
#pragma unroll
  for (int i = 0; i < 4; ++i)
#pragma unroll
    for (int j = 0; j < 2; ++j) acc[i][j] = {0.f, 0.f, 0.f, 0.f};

  u16x8 xa, xb;  // prefetch set X (even tiles)
  u16x8 ya, yb;  // prefetch set Y (odd tiles)

#define LOAD_X(kt)                      \
  xa = *(const u16x8*)(pA + (kt) * 32); \
  xb = *(const u16x8*)(pB + (kt) * 32);
#define LOAD_Y(kt)                      \
  ya = *(const u16x8*)(pA + (kt) * 32); \
  yb = *(const u16x8*)(pB + (kt) * 32);
#define STORE_X(buf)                \
  *(u16x8*)&As[buf][srow][sc] = xa; \
  *(u16x8*)&Bs[buf][srow][sc] = xb;
#define STORE_Y(buf)                \
  *(u16x8*)&As[buf][srow][sc] = ya; \
  *(u16x8*)&Bs[buf][srow][sc] = yb;
#define COMPUTE(buf)                                                        \
  {                                                                         \
    bf16x8 af[4], bfr[2];                                                   \
    _Pragma("unroll") for (int fr = 0; fr < 4; ++fr) af[fr] =               \
        *(const bf16x8*)&As[buf][wr * 64 + fr * 16 + lr][lg * 8];           \
    _Pragma("unroll") for (int fc = 0; fc < 2; ++fc) bfr[fc] =              \
        *(const bf16x8*)&Bs[buf][wc * 32 + fc * 16 + lr][lg * 8];           \
    _Pragma("unroll") for (int fr = 0; fr < 4; ++fr)                        \
        _Pragma("unroll") for (int fc = 0; fc < 2; ++fc) acc[fr][fc] =      \
            __builtin_amdgcn_mfma_f32_16x16x32_bf16(af[fr], bfr[fc],        \
                                                    acc[fr][fc], 0, 0, 0);  \
  }

  LOAD_X(0);
  LOAD_Y(1);
  STORE_X(0);
  __syncthreads();

  for (int t = 0; t < NT; t += 2) {
    if (t + 2 < NT) LOAD_X(t + 2);
    COMPUTE(0);
    STORE_Y(1);
    __syncthreads();
    if (t + 3 < NT) LOAD_Y(t + 3);
    COMPUTE(1);
    if (t + 2 < NT) STORE_X(0);
    __syncthreads();
  }
#undef LOAD_X
#undef LOAD_Y
#undef STORE_X
#undef STORE_Y
#undef COMPUTE

  // epilogue: bias + packed-row store
  float biasv[2];
#pragma unroll
  for (int fc = 0; fc < 2; ++fc)
    biasv[fc] = bias[bn * 128 + wc * 32 + fc * 16 + lr];

#pragma unroll
  for (int fr = 0; fr < 4; ++fr) {
#pragma unroll
    for (int fc = 0; fc < 2; ++fc) {
      const int col = bn * 128 + wc * 32 + fc * 16 + lr;
#pragma unroll
      for (int j = 0; j < 4; ++j) {
        const int row = bm * 128 + wr * 64 + fr * 16 + lg * 4 + j;
        const int bb = row / rpb;
        const int rr = row - bb * rpb;
        out[(size_t)bb * (ROWS_OUT * cH) + (size_t)(row_off + rr) * cH + col] =
            acc[fr][fc][j] + biasv[fc];
      }
    }
  }
}

__global__ __launch_bounds__(512) void gemms_kernel(
    const unsigned short* __restrict__ selfeat,
    const unsigned short* __restrict__ Wt_vs,
    const unsigned short* __restrict__ text_bf,
    const unsigned short* __restrict__ Wt_tx, const float* __restrict__ b_vs,
    const float* __restrict__ b_tx, float* __restrict__ out) {
  __shared__ unsigned short As[2][128][40];
  __shared__ unsigned short Bs[2][128][40];
  const int blk = blockIdx.x;
  if (blk < 128) {
    // XCD-chunked swizzle: hw blocks with blk%8==x handle bm in [4x,4x+4),
    // all bn -> A-panels fetched once per XCD L2 instead of 4x from HBM.
    const int w = ((blk & 7) << 4) | (blk >> 3);
    mfma_gemm_body<1024>(selfeat, Wt_vs, b_vs, out, w >> 2, w & 3, 128, 0, As,
                         Bs);
  } else {
    // linear_text: [640,512] @ Wt_tx[512,512]^T -> rows [128,148)/batch
    const int t = blk - 128;  // 20 blocks: 5 x 4
    mfma_gemm_body<512>(text_bf, Wt_tx, b_tx, out, t >> 2, t & 3, cL, cK, As,
                        Bs);
  }
}

// ---------------------------------------------------------------------------
extern "C" void kernel_launch(void* const* d_in, const int* in_sizes, int n_in,
                              void* d_out, int out_size, void* d_ws,
                              size_t ws_size, hipStream_t stream) {
  const float* boxes = (const float*)d_in[0];
  const float* feature = (const float*)d_in[1];
  const float* text = (const float*)d_in[2];
  const float* W_vs = (const float*)d_in[3];
  const float* b_vs = (const float*)d_in[4];
  const float* W_tx = (const float*)d_in[5];
  const float* b_tx = (const float*)d_in[6];

  float* out = (float*)d_out;                           // [B, 148, 512]
  float* out_boxes = out + (size_t)cB * ROWS_OUT * cH;  // [B, K, 3, 6]

  // workspace layout (bytes):
  //   idx      @ 0        (16 KB)
  //   selfeat  @ 16384    [4096,1024] bf16 (8 MB)
  //   Wt_vs    @ 8404992  [512][1024] bf16 (1 MB)
  //   Wt_tx    @ 9453568  [512][512]  bf16 (512 KB)
  //   text_bf  @ 9977856  [640][512]  bf16 (640 KB)
  int* idx = (int*)d_ws;
  unsigned short* selfeat = (unsigned short*)((char*)d_ws + 16384);
  unsigned short* Wt_vs = (unsigned short*)((char*)d_ws + 8404992);
  unsigned short* Wt_tx = (unsigned short*)((char*)d_ws + 9453568);
  unsigned short* text_bf = (unsigned short*)((char*)d_ws + 9977856);

  // 1) top-K + box gather + weight/text prep (304 blocks, 512 thr)
  front_kernel<<<cB + 272, FTHREADS, 0, stream>>>(
      boxes, W_vs, W_tx, text, idx, out_boxes, Wt_vs, Wt_tx, text_bf);

  // 2) gather selected feature columns -> sel_feat bf16 [B*K, D]
  {
    dim3 grid(2, 32, 32);
    gather_feat_kernel<<<grid, 256, 0, stream>>>(feature, idx, selfeat);
  }

  // 3) both GEMMs in one launch (128 + 20 blocks, 512 threads)
  gemms_kernel<<<148, 512, 0, stream>>>(selfeat, Wt_vs, text_bf, Wt_tx, b_vs,
                                        b_tx, out);
}